// Round 6
// baseline (533.437 us; speedup 1.0000x reference)
//
#include <hip/hip_runtime.h>
#include <hip/hip_bf16.h>
#include <stdint.h>

#define IN_F 4096
#define OUT_F 4096
#define MTOK 8192
#define TOPX_N 10
#define NUMVALS 200000
#define CSR_BLOCKS ((NUMVALS + 255) / 256)
#define CVT_BLOCKS ((MTOK * IN_F / 8) / 256)   /* 16384 */

typedef __bf16 bf16x8 __attribute__((ext_vector_type(8)));
typedef float f32x4 __attribute__((ext_vector_type(4)));

__device__ __forceinline__ void gld_lds16(const void* g, void* l) {
    __builtin_amdgcn_global_load_lds((const __attribute__((address_space(1))) void*)g,
                                     (__attribute__((address_space(3))) void*)l, 16, 0, 0);
}

// ---------------------------------------------------------------------------
// 1) Dequant: W^T[j][k] = lut[j][code(k,j)], bf16, layout (OUT_F, IN_F).
// ---------------------------------------------------------------------------
__global__ __launch_bounds__(256) void k_dequant(const int* __restrict__ qw,
                                                 const float* __restrict__ lut,
                                                 __bf16* __restrict__ Wt) {
    __shared__ int qs[64 * 65];
    __shared__ float ls[64 * 16];
    const int b = blockIdx.x;
    const int jc = (b & 63) * 64;
    const int wc = (b >> 6) * 64;
    const int t = threadIdx.x;

    {
        float4 v = *(const float4*)(lut + (size_t)(jc + (t >> 2)) * 16 + (t & 3) * 4);
        *(float4*)(ls + (t >> 2) * 16 + (t & 3) * 4) = v;
    }
#pragma unroll
    for (int p = 0; p < 4; ++p) {
        int idx = t + p * 256;
        int row = idx >> 4;
        int c4 = (idx & 15) * 4;
        int4 v = *(const int4*)(qw + (size_t)(wc + row) * OUT_F + jc + c4);
        int base = row * 65 + c4;
        qs[base] = v.x; qs[base + 1] = v.y; qs[base + 2] = v.z; qs[base + 3] = v.w;
    }
    __syncthreads();

    const int wave = t >> 6, lane = t & 63;
#pragma unroll
    for (int i = 0; i < 16; ++i) {
        const int c = wave * 16 + i;
        const unsigned q = (unsigned)qs[lane * 65 + c];
        const float* lp = ls + c * 16;
        bf16x8 v;
#pragma unroll
        for (int e = 0; e < 8; ++e) v[e] = (__bf16)lp[(q >> (4 * e)) & 15];
        *(bf16x8*)(Wt + (size_t)(jc + c) * IN_F + (size_t)(wc + lane) * 8) = v;
    }
}

// ---------------------------------------------------------------------------
// 2) Fused prep: x fp32->bf16 convert + CSR outliers + topX (one dispatch,
//    complementary resource profiles; must follow k_dequant).
// ---------------------------------------------------------------------------
__device__ __forceinline__ void bf16_cas_add(__bf16* Wt, size_t elem, float v) {
    unsigned* wp = (unsigned*)Wt + (elem >> 1);
    unsigned sh = (unsigned)(elem & 1) * 16;
    unsigned old = *wp, assumed;
    do {
        assumed = old;
        union { unsigned u; float f; } cv;
        cv.u = ((assumed >> sh) & 0xFFFFu) << 16;      // bf16 -> f32 (exact)
        __bf16 nb = (__bf16)(cv.f + v);
        unsigned nh = *(unsigned short*)&nb;
        unsigned newv = (assumed & ~(0xFFFFu << sh)) | ((unsigned)nh << sh);
        old = atomicCAS(wp, assumed, newv);
    } while (old != assumed);
}

__global__ __launch_bounds__(256) void k_prep(const float* __restrict__ x,
                                              __bf16* __restrict__ xb,
                                              const int* __restrict__ rows,
                                              const int* __restrict__ cols,
                                              const float* __restrict__ vals,
                                              const float* __restrict__ fr,
                                              const int* __restrict__ fri,
                                              __bf16* __restrict__ Wt) {
    const int b = blockIdx.x;
    if (b < CVT_BLOCKS) {
        size_t t = (size_t)b * 256 + threadIdx.x;
        const float4* p = (const float4*)x + 2 * t;
        float4 a = p[0], c = p[1];
        bf16x8 v;
        v[0] = (__bf16)a.x; v[1] = (__bf16)a.y; v[2] = (__bf16)a.z; v[3] = (__bf16)a.w;
        v[4] = (__bf16)c.x; v[5] = (__bf16)c.y; v[6] = (__bf16)c.z; v[7] = (__bf16)c.w;
        ((bf16x8*)xb)[t] = v;
    } else if (b < CVT_BLOCKS + CSR_BLOCKS) {
        int n = (b - CVT_BLOCKS) * 256 + threadIdx.x;
        if (n >= NUMVALS) return;
        int lo = 0, hi = OUT_F + 1;
        while (lo < hi) {
            int mid = (lo + hi) >> 1;
            if (rows[mid] <= n) lo = mid + 1; else hi = mid;
        }
        int r = lo - 1;
        bf16_cas_add(Wt, (size_t)r * IN_F + cols[n], vals[n]);
    } else {
        int i = (b - CVT_BLOCKS - CSR_BLOCKS) * 256 + threadIdx.x;
        if (i >= IN_F) return;
#pragma unroll
        for (int t = 0; t < TOPX_N; ++t) {
            int j = fri[t];
            bf16_cas_add(Wt, (size_t)j * IN_F + i, fr[(size_t)i * TOPX_N + t]);
        }
    }
}

// ---------------------------------------------------------------------------
// 3) GEMM — R1 tri-buffer schedule DEEPENED to a 4-buffer ring (only delta
//    vs the verified 302-us kernel). Rationale: the boundary vmcnt(4) needs
//    tile t landed after only ~620 SIMD-cycles of cover, but HBM-miss
//    latency is ~900 cyc (m126) and FETCH_SIZE (305 MB vs 96 MB logical)
//    shows many staging loads miss L2. Staging t+3 (vmcnt(8), 3 compute
//    windows ~930+ cyc of cover) hides full HBM latency. WAR safety is the
//    tri-buffer induction one step deeper: buf (t+3)&3 last read in iter
//    t-1, reads register-complete before each wave's iter-t barrier, stage
//    issued after that barrier. LDS 4 x 32 KB = 128 KB, still 1 block/CU.
//    R2 (hand-phased) and R4 (coarse windows + vmcnt(0) drain) both
//    regressed — structure otherwise frozen.
//
//    T2 swizzle (0 conflicts measured): 16-row x 64B window, 16B granule
//    (r,g) at slot P = ((5r+g)&7) + 8g + 32*(r>>3); DMA dest linear
//    (lane*16), global source inverse-swizzled, reads swizzled.
// ---------------------------------------------------------------------------
#define BK_G 32
#define NKT (IN_F / BK_G)          /* 128 K-tiles */
#define TILE_BYTES 16384           /* 256 rows x 64 B */
#define MFMA_ __builtin_amdgcn_mfma_f32_16x16x32_bf16

__global__ __launch_bounds__(512, 2) void k_gemm(const __bf16* __restrict__ A,
                                                 const __bf16* __restrict__ Bt,
                                                 const float* __restrict__ bias,
                                                 float* __restrict__ C) {
    __shared__ __align__(1024) char smem[4][2][TILE_BYTES];   // [buf][A/B][tile] = 128 KiB

    const int tid = threadIdx.x;
    const int wave = tid >> 6, lane = tid & 63;
    const int wm = wave >> 2, wn = wave & 3;

    // XCD-aware swizzle: 512 blocks, 8 XCDs, 64 contiguous per XCD (n-fast).
    const int bid = blockIdx.x;
    const int swz = (bid & 7) * 64 + (bid >> 3);
    const int n0 = (swz & 15) * 256;
    const int m0 = (swz >> 4) * 256;

    // ---- staging map: lane -> (row_local, granule) it must fetch ----
    const int q = lane & 7, g = (lane >> 3) & 3, rh = lane >> 5;
    const int rloc = ((5 * (q - g + 8)) & 7) + 8 * rh;   // 0..15
    const int w0 = wave * 2;                             // this wave's 2 windows

    const char* gA0 = (const char*)(A  + (size_t)(m0 + w0 * 16 + rloc) * IN_F) + g * 16;
    const char* gA1 = gA0 + 16 * IN_F * 2;
    const char* gB0 = (const char*)(Bt + (size_t)(n0 + w0 * 16 + rloc) * IN_F) + g * 16;
    const char* gB1 = gB0 + 16 * IN_F * 2;
    char* lA = (char*)smem[0][0] + w0 * 1024;            // + boff selects buffer
    char* lB = (char*)smem[0][1] + w0 * 1024;

    // ---- read map: frag (row = wbase + m*16 + lrow, granule kk) ----
    const int lrow = lane & 15, kk = lane >> 4;
    const int rdc = ((5 * lrow + kk) & 7) * 16 + kk * 128 + (lrow >> 3) * 512;
    const int rdA = wm * 8192 + rdc;                     // + m*1024 immediate
    const int rdB = wn * 4096 + rdc;                     // + n*1024 immediate

#define STAGE(boff, koff) do {                               \
        gld_lds16(gA0 + (koff), lA + (boff));                \
        gld_lds16(gA1 + (koff), lA + (boff) + 1024);         \
        gld_lds16(gB0 + (koff), lB + (boff));                \
        gld_lds16(gB1 + (koff), lB + (boff) + 1024);         \
    } while (0)

#define COMPUTE(boff) do {                                                                     \
        const char* pA = (const char*)smem[0][0] + (boff) + rdA;                               \
        const char* pB = (const char*)smem[0][1] + (boff) + rdB;                               \
        bf16x8 bfr[4], af0[4], af1[4];                                                         \
        _Pragma("unroll") for (int n = 0; n < 4; ++n) bfr[n] = *(const bf16x8*)(pB + n * 1024);\
        _Pragma("unroll") for (int m = 0; m < 4; ++m) af0[m] = *(const bf16x8*)(pA + m * 1024);\
        _Pragma("unroll") for (int m = 0; m < 4; ++m) af1[m] = *(const bf16x8*)(pA + 4096 + m * 1024);\
        __builtin_amdgcn_s_setprio(1);                                                         \
        _Pragma("unroll") for (int m = 0; m < 4; ++m)                                          \
            _Pragma("unroll") for (int n = 0; n < 4; ++n)                                      \
                acc[m][n] = MFMA_(af0[m], bfr[n], acc[m][n], 0, 0, 0);                         \
        _Pragma("unroll") for (int m = 0; m < 4; ++m)                                          \
            _Pragma("unroll") for (int n = 0; n < 4; ++n)                                      \
                acc[m + 4][n] = MFMA_(af1[m], bfr[n], acc[m + 4][n], 0, 0, 0);                 \
        __builtin_amdgcn_s_setprio(0);                                                         \
    } while (0)

    f32x4 acc[8][4] = {};

    // prologue: tiles 0,1,2 -> bufs 0,1,2 (12 loads in flight)
    STAGE(0, 0);
    STAGE(32768, 64);
    STAGE(65536, 128);

    int cboff = 0, sboff = 98304;
    for (int t = 0; t < NKT - 2; ++t) {
        // tile t landed (tiles t+1, t+2 = 8 loads may remain in flight)
        asm volatile("s_waitcnt vmcnt(8)" ::: "memory");
        __builtin_amdgcn_s_barrier();
        asm volatile("" ::: "memory");     // keep stage/ds_reads below the barrier
        if (t + 3 < NKT) STAGE(sboff, (t + 3) * 64);
        COMPUTE(cboff);
        cboff = cboff == 98304 ? 0 : cboff + 32768;
        sboff = sboff == 98304 ? 0 : sboff + 32768;
    }
    // tile NKT-2: 8 loads outstanding; need the oldest 4 (this tile) landed
    asm volatile("s_waitcnt vmcnt(4)" ::: "memory");
    __builtin_amdgcn_s_barrier();
    asm volatile("" ::: "memory");
    COMPUTE(cboff);
    cboff = cboff == 98304 ? 0 : cboff + 32768;
    // tile NKT-1: drain
    asm volatile("s_waitcnt vmcnt(0)" ::: "memory");
    __builtin_amdgcn_s_barrier();
    asm volatile("" ::: "memory");
    COMPUTE(cboff);

    // ---- epilogue: C/D layout col = lane&15, row = (lane>>4)*4 + r ----
    const int m0w = m0 + wm * 128;
    const int n0w = n0 + wn * 64;
#pragma unroll
    for (int n = 0; n < 4; ++n) {
        const int col = n0w + n * 16 + lrow;
        const float bj = bias[col];
#pragma unroll
        for (int m = 0; m < 8; ++m) {
            const int row = m0w + m * 16 + kk * 4;
#pragma unroll
            for (int r = 0; r < 4; ++r)
                C[(size_t)(row + r) * OUT_F + col] = acc[m][n][r] + bj;
        }
    }
#undef STAGE
#undef COMPUTE
}

extern "C" void kernel_launch(void* const* d_in, const int* in_sizes, int n_in,
                              void* d_out, int out_size, void* d_ws, size_t ws_size,
                              hipStream_t stream) {
    const float* x         = (const float*)d_in[0];
    const int*   qweight   = (const int*)d_in[1];
    const float* lut       = (const float*)d_in[2];
    const float* bias      = (const float*)d_in[3];
    const int*   rows      = (const int*)d_in[4];
    const int*   cols      = (const int*)d_in[5];
    const float* vals      = (const float*)d_in[6];
    const float* full_rows = (const float*)d_in[7];
    const int*   fri       = (const int*)d_in[8];
    float* out = (float*)d_out;

    __bf16* Wt = (__bf16*)d_ws;                                        // 32 MB: W^T (OUT_F, IN_F)
    __bf16* xb = (__bf16*)((char*)d_ws + (size_t)OUT_F * IN_F * 2);    // 64 MB: x bf16 (8192, 4096)

    k_dequant<<<dim3(64 * 8), 256, 0, stream>>>(qweight, lut, Wt);
    k_prep<<<dim3(CVT_BLOCKS + CSR_BLOCKS + IN_F / 256), 256, 0, stream>>>(
        x, xb, rows, cols, vals, full_rows, fri, Wt);
    k_gemm<<<dim3((OUT_F / 256) * (MTOK / 256)), 512, 0, stream>>>(xb, Wt, bias, out);
}

// Round 7
// 515.270 us; speedup vs baseline: 1.0353x; 1.0353x over previous
//
#include <hip/hip_runtime.h>
#include <hip/hip_bf16.h>
#include <stdint.h>

#define IN_F 4096
#define OUT_F 4096
#define MTOK 8192
#define TOPX_N 10
#define NUMVALS 200000
#define CSR_BLOCKS ((NUMVALS + 255) / 256)
#define CVT_BLOCKS ((MTOK * IN_F / 8) / 256)   /* 16384 */

typedef __bf16 bf16x8 __attribute__((ext_vector_type(8)));
typedef float f32x4 __attribute__((ext_vector_type(4)));

__device__ __forceinline__ void gld_lds16(const void* g, void* l) {
    __builtin_amdgcn_global_load_lds((const __attribute__((address_space(1))) void*)g,
                                     (__attribute__((address_space(3))) void*)l, 16, 0, 0);
}

// ---------------------------------------------------------------------------
// 1) Dequant: W^T[j][k] = lut[j][code(k,j)], bf16, layout (OUT_F, IN_F).
// ---------------------------------------------------------------------------
__global__ __launch_bounds__(256) void k_dequant(const int* __restrict__ qw,
                                                 const float* __restrict__ lut,
                                                 __bf16* __restrict__ Wt) {
    __shared__ int qs[64 * 65];
    __shared__ float ls[64 * 16];
    const int b = blockIdx.x;
    const int jc = (b & 63) * 64;
    const int wc = (b >> 6) * 64;
    const int t = threadIdx.x;

    {
        float4 v = *(const float4*)(lut + (size_t)(jc + (t >> 2)) * 16 + (t & 3) * 4);
        *(float4*)(ls + (t >> 2) * 16 + (t & 3) * 4) = v;
    }
#pragma unroll
    for (int p = 0; p < 4; ++p) {
        int idx = t + p * 256;
        int row = idx >> 4;
        int c4 = (idx & 15) * 4;
        int4 v = *(const int4*)(qw + (size_t)(wc + row) * OUT_F + jc + c4);
        int base = row * 65 + c4;
        qs[base] = v.x; qs[base + 1] = v.y; qs[base + 2] = v.z; qs[base + 3] = v.w;
    }
    __syncthreads();

    const int wave = t >> 6, lane = t & 63;
#pragma unroll
    for (int i = 0; i < 16; ++i) {
        const int c = wave * 16 + i;
        const unsigned q = (unsigned)qs[lane * 65 + c];
        const float* lp = ls + c * 16;
        bf16x8 v;
#pragma unroll
        for (int e = 0; e < 8; ++e) v[e] = (__bf16)lp[(q >> (4 * e)) & 15];
        *(bf16x8*)(Wt + (size_t)(jc + c) * IN_F + (size_t)(wc + lane) * 8) = v;
    }
}

// ---------------------------------------------------------------------------
// 2) Fused prep: x fp32->bf16 convert + CSR outliers + topX (one dispatch).
// ---------------------------------------------------------------------------
__device__ __forceinline__ void bf16_cas_add(__bf16* Wt, size_t elem, float v) {
    unsigned* wp = (unsigned*)Wt + (elem >> 1);
    unsigned sh = (unsigned)(elem & 1) * 16;
    unsigned old = *wp, assumed;
    do {
        assumed = old;
        union { unsigned u; float f; } cv;
        cv.u = ((assumed >> sh) & 0xFFFFu) << 16;      // bf16 -> f32 (exact)
        __bf16 nb = (__bf16)(cv.f + v);
        unsigned nh = *(unsigned short*)&nb;
        unsigned newv = (assumed & ~(0xFFFFu << sh)) | ((unsigned)nh << sh);
        old = atomicCAS(wp, assumed, newv);
    } while (old != assumed);
}

__global__ __launch_bounds__(256) void k_prep(const float* __restrict__ x,
                                              __bf16* __restrict__ xb,
                                              const int* __restrict__ rows,
                                              const int* __restrict__ cols,
                                              const float* __restrict__ vals,
                                              const float* __restrict__ fr,
                                              const int* __restrict__ fri,
                                              __bf16* __restrict__ Wt) {
    const int b = blockIdx.x;
    if (b < CVT_BLOCKS) {
        size_t t = (size_t)b * 256 + threadIdx.x;
        const float4* p = (const float4*)x + 2 * t;
        float4 a = p[0], c = p[1];
        bf16x8 v;
        v[0] = (__bf16)a.x; v[1] = (__bf16)a.y; v[2] = (__bf16)a.z; v[3] = (__bf16)a.w;
        v[4] = (__bf16)c.x; v[5] = (__bf16)c.y; v[6] = (__bf16)c.z; v[7] = (__bf16)c.w;
        ((bf16x8*)xb)[t] = v;
    } else if (b < CVT_BLOCKS + CSR_BLOCKS) {
        int n = (b - CVT_BLOCKS) * 256 + threadIdx.x;
        if (n >= NUMVALS) return;
        int lo = 0, hi = OUT_F + 1;
        while (lo < hi) {
            int mid = (lo + hi) >> 1;
            if (rows[mid] <= n) lo = mid + 1; else hi = mid;
        }
        int r = lo - 1;
        bf16_cas_add(Wt, (size_t)r * IN_F + cols[n], vals[n]);
    } else {
        int i = (b - CVT_BLOCKS - CSR_BLOCKS) * 256 + threadIdx.x;
        if (i >= IN_F) return;
#pragma unroll
        for (int t = 0; t < TOPX_N; ++t) {
            int j = fri[t];
            bf16_cas_add(Wt, (size_t)j * IN_F + i, fr[(size_t)i * TOPX_N + t]);
        }
    }
}

// ---------------------------------------------------------------------------
// 3) GEMM — faithful m201 8-phase port. C(8192x4096)=A*B^T+bias, bf16.
//    BM=BN=256, BK=64, 512 thr (8 waves 2Mx4N), per-wave 128x64.
//    LDS 128 KiB = 2 buf x {A 32K, B 32K}; half-tile = 128 rows = 16 KiB.
//    Iteration = 2 K-tiles (T0=2i in buf0 phases 1-4, T1=2i+1 in buf1
//    phases 5-8). Phase = {ds-reads; 1 half-tile stage (2 gld_lds);
//    [lgkm8 if 12 reads]; barrier; lgkm0; setprio1; 16 MFMA; setprio0;
//    barrier}. Stage slots: P1:Ah0(2i+1) P2:Ah1(2i+1) P3:Bh0(2i+2)
//    P4:Bh1(2i+2) P5:Ah0(2i+2) P6:Ah1(2i+2) P7:Bh0(2i+3) P8:Bh1(2i+3).
//    WAR audit: every stage targets a region whose last read's closing
//    barrier has passed (buf0 B dies P2, A dies P3; buf1 B dies P6, A P7);
//    stage/read regions within a phase are disjoint. vmcnt(4)+barrier at
//    P4/P8 only (2 half-tiles in flight): P4 guarantees T1 fully landed
//    (staged P7,P8 prev + P1,P2 cur) before P5; P8 guarantees T0+2 before
//    next P1. Memory fence ONLY after the P4/P8 vmcnt-barriers (the two
//    unsafe hoist points) — R2's fence-at-every-barrier killed the
//    interleave and is the identified cause of its regression.
//
//    Swizzle (generalizes the 0-conflict R1 map to 8 granules/row):
//    8-row x 128B window = 64 slots; (r,g) at slot ((r+g)&7)+8g.
//    Staging identity: lane l writes (r=((l&7)-(l>>3))&7, g=l>>3) at slot l
//    -> linear DMA dest; reads use the swizzled offset. Each 8-lane phase
//    of a ds_read_b128 covers all 32 banks once -> conflict-free.
// ---------------------------------------------------------------------------
#define BK_G 64
#define ROWB (IN_F * 2)            /* 8192 B per row */
#define HB   ((size_t)128 * ROWB)  /* half-tile row offset: 128 rows */
#define MFMA_ __builtin_amdgcn_mfma_f32_16x16x32_bf16

#define LGKM0 asm volatile("s_waitcnt lgkmcnt(0)")
#define LGKM8 asm volatile("s_waitcnt lgkmcnt(8)")
#define BAR   __builtin_amdgcn_s_barrier()
#define VMC4  asm volatile("s_waitcnt vmcnt(4)" ::: "memory")
#define VMC0  asm volatile("s_waitcnt vmcnt(0)" ::: "memory")
#define MEMF  asm volatile("" ::: "memory")
#define PRIO1 __builtin_amdgcn_s_setprio(1)
#define PRIO0 __builtin_amdgcn_s_setprio(0)

__global__ __launch_bounds__(512, 2) void k_gemm(const __bf16* __restrict__ A,
                                                 const __bf16* __restrict__ Bt,
                                                 const float* __restrict__ bias,
                                                 float* __restrict__ C) {
    __shared__ __align__(1024) char smem[2][2][32768];   // [buf][A/B] = 128 KiB
    char* const sm = (char*)smem;

    const int tid = threadIdx.x;
    const int wv = tid >> 6, l = tid & 63;
    const int wm = wv >> 2, wn = wv & 3;

    // XCD-aware swizzle: 512 blocks, 8 XCDs, 64 contiguous per XCD.
    const int bid = blockIdx.x;
    const int swz = (bid & 7) * 64 + (bid >> 3);
    const int n0 = (swz & 15) * 256;
    const int m0 = (swz >> 4) * 256;

    // ---- staging map: lane l -> (row rloc, granule g) at linear slot l ----
    const int g = l >> 3;                    // 0..7
    const int rloc = ((l & 7) - g) & 7;      // 0..7
    const int ld0 = wv * 1024 + l * 16;      // window wv, slot l (2nd load +8192)
    const char* pa = (const char*)A  + (size_t)(m0 + wv * 8 + rloc) * ROWB + g * 16;
    const char* pb = (const char*)Bt + (size_t)(n0 + wv * 8 + rloc) * ROWB + g * 16;

#define STG(srcp, dstoff) do {                                    \
        gld_lds16((srcp), sm + (dstoff) + ld0);                   \
        gld_lds16((srcp) + 64 * ROWB, sm + (dstoff) + ld0 + 8192);\
    } while (0)

    // ---- read map: frag row = W + lrow, k-slice ks -> granule ks*4+kk ----
    const int lrow = l & 15, kk = l >> 4;
    const int rd0 = (lrow >> 3) * 1024 + ((((lrow & 7) + kk) & 7)) * 16 + kk * 128;
    const int rd1 = (lrow >> 3) * 1024 + ((((lrow & 7) + kk + 4) & 7)) * 16 + (kk + 4) * 128;
    const int baA = wm * 16384;              // + buf + m*2048 + rd{0,1}
    const int baB = 32768 + wn * 8192;       // + buf + n*2048 + rd{0,1}

    f32x4 acc[8][4] = {};
    bf16x8 af[4][2], bfr[4][2];

#define RD_B(buf, nlo) do { _Pragma("unroll") for (int n_ = 0; n_ < 2; ++n_) {          \
        bfr[(nlo) + n_][0] = *(const bf16x8*)(sm + (buf) + baB + ((nlo) + n_) * 2048 + rd0); \
        bfr[(nlo) + n_][1] = *(const bf16x8*)(sm + (buf) + baB + ((nlo) + n_) * 2048 + rd1); } } while (0)
#define RD_A(buf, mlo) do { _Pragma("unroll") for (int m_ = 0; m_ < 4; ++m_) {          \
        af[m_][0] = *(const bf16x8*)(sm + (buf) + baA + ((mlo) + m_) * 2048 + rd0);     \
        af[m_][1] = *(const bf16x8*)(sm + (buf) + baA + ((mlo) + m_) * 2048 + rd1); } } while (0)
#define MFMA_Q(MB, NB) do { _Pragma("unroll") for (int m_ = 0; m_ < 4; ++m_)            \
        _Pragma("unroll") for (int n_ = 0; n_ < 2; ++n_) {                              \
            acc[(MB) + m_][(NB) + n_] = MFMA_(af[m_][0], bfr[(NB) + n_][0], acc[(MB) + m_][(NB) + n_], 0, 0, 0); \
            acc[(MB) + m_][(NB) + n_] = MFMA_(af[m_][1], bfr[(NB) + n_][1], acc[(MB) + m_][(NB) + n_], 0, 0, 0); } } while (0)

    // ---- prologue: tile0 (4 halves) + tile1 B halves; vmcnt(4) ----
    STG(pb, 32768); STG(pb + HB, 49152);              // t0 B
    STG(pa, 0);     STG(pa + HB, 16384);              // t0 A
    STG(pb + 128, 98304); STG(pb + 128 + HB, 114688); // t1 B
    VMC4; BAR; MEMF;

    for (int i = 0; i < 32; ++i) {
        const bool stg = (i < 31);
        // ---- P1: 12 reads (T0 in buf0) + stage Ah0(2i+1) ----
        RD_B(0, 0); RD_A(0, 0);
        STG(pa + 128, 65536);
        LGKM8; BAR; LGKM0;
        PRIO1; MFMA_Q(0, 0); PRIO0; BAR;
        // ---- P2: 4 reads + stage Ah1(2i+1) ----
        RD_B(0, 2);
        STG(pa + 128 + HB, 81920);
        BAR; LGKM0;
        PRIO1; MFMA_Q(0, 2); PRIO0; BAR;
        // ---- P3: 8 reads + stage Bh0(2i+2) ----
        RD_A(0, 4);
        if (stg) STG(pb + 256, 32768);
        BAR; LGKM0;
        PRIO1; MFMA_Q(4, 2); PRIO0; BAR;
        // ---- P4: stage Bh1(2i+2); vmcnt before closing barrier ----
        if (stg) STG(pb + 256 + HB, 49152);
        BAR;
        PRIO1; MFMA_Q(4, 0); PRIO0;
        if (stg) { VMC4; } else { VMC0; }
        BAR; MEMF;
        // ---- P5: 12 reads (T1 in buf1) + stage Ah0(2i+2) ----
        RD_B(65536, 0); RD_A(65536, 0);
        if (stg) STG(pa + 256, 0);
        LGKM8; BAR; LGKM0;
        PRIO1; MFMA_Q(0, 0); PRIO0; BAR;
        // ---- P6: 4 reads + stage Ah1(2i+2) ----
        RD_B(65536, 2);
        if (stg) STG(pa + 256 + HB, 16384);
        BAR; LGKM0;
        PRIO1; MFMA_Q(0, 2); PRIO0; BAR;
        // ---- P7: 8 reads + stage Bh0(2i+3) ----
        RD_A(65536, 4);
        if (stg) STG(pb + 384, 98304);
        BAR; LGKM0;
        PRIO1; MFMA_Q(4, 2); PRIO0; BAR;
        // ---- P8: stage Bh1(2i+3); vmcnt(4) + closing barrier ----
        if (stg) STG(pb + 384 + HB, 114688);
        BAR;
        PRIO1; MFMA_Q(4, 0); PRIO0;
        if (stg) { VMC4; BAR; MEMF; }
        pa += 256; pb += 256;
    }

    // ---- epilogue: C/D layout col = lane&15, row = (lane>>4)*4 + r ----
    const int m0w = m0 + wm * 128;
    const int n0w = n0 + wn * 64;
#pragma unroll
    for (int n = 0; n < 4; ++n) {
        const int col = n0w + n * 16 + lrow;
        const float bj = bias[col];
#pragma unroll
        for (int m = 0; m < 8; ++m) {
            const int row = m0w + m * 16 + kk * 4;
#pragma unroll
            for (int r = 0; r < 4; ++r)
                C[(size_t)(row + r) * OUT_F + col] = acc[m][n][r] + bj;
        }
    }
#undef STG
#undef RD_A
#undef RD_B
#undef MFMA_Q
}

extern "C" void kernel_launch(void* const* d_in, const int* in_sizes, int n_in,
                              void* d_out, int out_size, void* d_ws, size_t ws_size,
                              hipStream_t stream) {
    const float* x         = (const float*)d_in[0];
    const int*   qweight   = (const int*)d_in[1];
    const float* lut       = (const float*)d_in[2];
    const float* bias      = (const float*)d_in[3];
    const int*   rows      = (const int*)d_in[4];
    const int*   cols      = (const int*)d_in[5];
    const float* vals      = (const float*)d_in[6];
    const float* full_rows = (const float*)d_in[7];
    const int*   fri       = (const int*)d_in[8];
    float* out = (float*)d_out;

    __bf16* Wt = (__bf16*)d_ws;                                        // 32 MB: W^T (OUT_F, IN_F)
    __bf16* xb = (__bf16*)((char*)d_ws + (size_t)OUT_F * IN_F * 2);    // 64 MB: x bf16 (8192, 4096)

    k_dequant<<<dim3(64 * 8), 256, 0, stream>>>(qweight, lut, Wt);
    k_prep<<<dim3(CVT_BLOCKS + CSR_BLOCKS + IN_F / 256), 256, 0, stream>>>(
        x, xb, rows, cols, vals, full_rows, fri, Wt);
    k_gemm<<<dim3((OUT_F / 256) * (MTOK / 256)), 512, 0, stream>>>(xb, Wt, bias, out);
}